// Round 4
// baseline (718.392 us; speedup 1.0000x reference)
//
#include <hip/hip_runtime.h>
#include <hip/hip_bf16.h>
#include <math.h>

// Perceiver: B=4,C=3,N=4096,E=256,H=8,FFE=1024,L=512,D=4,NCLS=1000,HS=2048
// bf16 MFMA everywhere GEMM-shaped; fp32 accum; fp32 LN/residual spine.

typedef __attribute__((ext_vector_type(8))) short s8v;   // 8 bf16 = 4 VGPR
typedef __attribute__((ext_vector_type(4))) float f32x4; // MFMA accum

__device__ __forceinline__ short f2b(float f) {
  union { float f; unsigned u; } a; a.f = f;
  unsigned r = a.u + 0x7fff + ((a.u >> 16) & 1);
  return (short)(r >> 16);
}
__device__ __forceinline__ float b2f(short s) {
  union { unsigned u; float f; } a; a.u = ((unsigned)(unsigned short)s) << 16;
  return a.f;
}

// async global->LDS, 16B per lane; LDS dest = uniform base + lane*16
__device__ __forceinline__ void gl16(const void* gp, void* lp) {
  __builtin_amdgcn_global_load_lds(
      (const __attribute__((address_space(1))) unsigned int*)gp,
      (__attribute__((address_space(3))) unsigned int*)lp, 16, 0, 0);
}

// ---------------- tokens(bf16) = conv1x1(x) + bias + pos ----------------
__global__ __launch_bounds__(256) void k_tokens(
    const float* __restrict__ x, const float* __restrict__ cw,
    const float* __restrict__ cb, const float* __restrict__ pe,
    short* __restrict__ tok)
{
  int idx = blockIdx.x * 256 + threadIdx.x;   // B*N*E
  int e = idx & 255;
  int n = (idx >> 8) & 4095;
  int b = idx >> 20;
  float s = cb[e] + pe[n * 256 + e];
#pragma unroll
  for (int c = 0; c < 3; ++c)
    s += x[b * 12288 + c * 4096 + n] * cw[e * 3 + c];
  tok[idx] = f2b(s);
}

// ---------------- transpose: in (R,C) [fp32 or bf16] -> out bf16 (C,R) ----
template<typename TI>
__global__ __launch_bounds__(256) void k_tr(
    const TI* __restrict__ in, short* __restrict__ out,
    int R, int C, long sIn, long sOut)
{
  __shared__ float t[32][33];
  const TI* ib = in + (long)blockIdx.z * sIn;
  short* ob = out + (long)blockIdx.z * sOut;
  int c0 = blockIdx.x * 32, r0 = blockIdx.y * 32;
  int tx = threadIdx.x & 31, ty = threadIdx.x >> 5; // 32 x 8
#pragma unroll
  for (int i = 0; i < 4; ++i)
    t[ty * 4 + i][tx] = (float)ib[(long)(r0 + ty * 4 + i) * C + c0 + tx];
  __syncthreads();
#pragma unroll
  for (int i = 0; i < 4; ++i)
    ob[(long)(c0 + ty * 4 + i) * R + r0 + tx] = f2b(t[tx][ty * 4 + i]);
}

// ---------------- fp32 -> bf16 flat convert ----------------
__global__ __launch_bounds__(256) void k_cvt(const float* __restrict__ in,
                                             short* __restrict__ out)
{
  int i = blockIdx.x * 256 + threadIdx.x;
  out[i] = f2b(in[i]);
}

// ---------------- bf16 MFMA BT-GEMM: C = A(MxK) @ Bt(NxK)^T ----------------
// 128x128 tile, BK=32, 256 thr. Prefetch pipeline. Requires K % 64 == 0.
// EPI: 0 = bf16 out, 1 = bias+exact-gelu bf16 out, 2 = fp32 out (partials).
template<int EPI>
__global__ __launch_bounds__(256) void k_mgemm(
    const short* __restrict__ A, const short* __restrict__ Bt,
    void* __restrict__ Cv, const float* __restrict__ bias,
    int K, int lda, int ldb, int ldc,
    long sA, long sB, long sC, int zdA, int zmA, int zdB, int zmB)
{
  __shared__ char As[8192];
  __shared__ char Bs[8192];
  int z = blockIdx.z;
  const short* Ab = A + ((long)((z / zdA) % zmA)) * sA;
  const short* Bb = Bt + ((long)((z / zdB) % zmB)) * sB;
  int t = threadIdx.x;
  int lane = t & 63, w = t >> 6;
  int wr = w >> 1, wc = w & 1;
  int g = lane >> 4, l15 = lane & 15;
  long row0 = (long)blockIdx.y * 128, col0 = (long)blockIdx.x * 128;
  const f32x4 zz = {0.f, 0.f, 0.f, 0.f};
  f32x4 acc[4][4];
#pragma unroll
  for (int m = 0; m < 4; ++m)
#pragma unroll
    for (int n = 0; n < 4; ++n) acc[m][n] = zz;

  auto mload = [&](s8v* aa, s8v* bb, int kk) {
#pragma unroll
    for (int i = 0; i < 2; ++i) {
      int r = i * 64 + (t >> 2), c = t & 3;
      aa[i] = *(const s8v*)&Ab[(row0 + r) * (long)lda + kk + c * 8];
      bb[i] = *(const s8v*)&Bb[(col0 + r) * (long)ldb + kk + c * 8];
    }
  };
  auto mstore = [&](s8v* aa, s8v* bb) {
#pragma unroll
    for (int i = 0; i < 2; ++i) {
      int r = i * 64 + (t >> 2), c = t & 3;
      int off = (r * 64 + c * 16) ^ ((r & 7) << 4);
      *(s8v*)&As[off] = aa[i];
      *(s8v*)&Bs[off] = bb[i];
    }
  };
  auto mcomp = [&]() {
    s8v af[4], bfr[4];
#pragma unroll
    for (int m = 0; m < 4; ++m) {
      int r = wr * 64 + m * 16 + l15;
      af[m] = *(const s8v*)&As[(r * 64 + g * 16) ^ ((r & 7) << 4)];
    }
#pragma unroll
    for (int n = 0; n < 4; ++n) {
      int r = wc * 64 + n * 16 + l15;
      bfr[n] = *(const s8v*)&Bs[(r * 64 + g * 16) ^ ((r & 7) << 4)];
    }
#pragma unroll
    for (int m = 0; m < 4; ++m)
#pragma unroll
      for (int n = 0; n < 4; ++n)
        acc[m][n] = __builtin_amdgcn_mfma_f32_16x16x32_bf16(af[m], bfr[n], acc[m][n], 0, 0, 0);
  };

  s8v a0[2], b0[2], a1[2], b1[2];
  mload(a0, b0, 0);
  for (int k0 = 0; k0 < K; k0 += 64) {
    __syncthreads(); mstore(a0, b0); __syncthreads();
    mload(a1, b1, k0 + 32);
    mcomp();
    __syncthreads(); mstore(a1, b1); __syncthreads();
    if (k0 + 64 < K) mload(a0, b0, k0 + 64);
    mcomp();
  }

  long zo = (long)z * sC;
#pragma unroll
  for (int m = 0; m < 4; ++m)
#pragma unroll
    for (int n = 0; n < 4; ++n)
#pragma unroll
      for (int r = 0; r < 4; ++r) {
        long rr = row0 + wr * 64 + m * 16 + g * 4 + r;
        long cc = col0 + wc * 64 + n * 16 + l15;
        float v = acc[m][n][r];
        if (EPI == 1) {
          v += bias[cc];
          v = 0.5f * v * (1.f + erff(v * 0.70710678118654752f));
        }
        if (EPI == 2)
          ((float*)Cv)[zo + rr * ldc + cc] = v;
        else
          ((short*)Cv)[zo + rr * ldc + cc] = f2b(v);
      }
}

// ---------------- MFMA flash attention v3 (head dim 256) ----------------
// 512 thr = 8 waves, ALL sharing one K/V tile stream (128 q rows/block).
// kv-split x4 across blocks; unnormalized bf16 O + fp32 (m,l) partials to
// global; k_fcomb merges. LDS 72KB -> 2 blocks/CU -> 4 waves/SIMD.
__global__ __launch_bounds__(512, 4) void k_mflash3(
    const short* __restrict__ Qp, const short* __restrict__ Kp,
    const short* __restrict__ Vtp, short* __restrict__ Opart,
    float* __restrict__ MLp,
    int nk, int ldq, int ldk, int ldvt,
    long qh, long qb, long kh, long kb, long vh, long vb, float scale)
{
  __shared__ char pool[73728]; // buf0 K@0 V@16K, buf1 K@32K V@48K, P@64K(8K)
  int t = threadIdx.x, lane = t & 63, w = t >> 6;
  int g = lane >> 4, l15 = lane & 15;
  int h = blockIdx.y, b = blockIdx.z;
  int kv = blockIdx.x & 3, qblk = blockIdx.x >> 2;
  const short* Q  = Qp  + (long)h * qh + (long)b * qb;
  const short* Kg = Kp  + (long)h * kh + (long)b * kb;
  const short* Vg = Vtp + (long)h * vh + (long)b * vb;
  char* Pw = pool + 65536 + w * 1024;
  int q0 = qblk * 128 + w * 16;
  int nkq = nk >> 2;          // keys per block
  int NIT = nkq >> 5;         // KVBLK = 32
  int k0base = kv * nkq;

  // Q fragments: A-frag row=l15, k = ks*32 + g*8
  const short* Qrow = Q + (long)(q0 + l15) * ldq + g * 8;
  s8v qf[8];
#pragma unroll
  for (int ks = 0; ks < 8; ++ks) qf[ks] = *(const s8v*)(Qrow + ks * 32);

  // staging sources (linear LDS dest + inverse-swizzled global source)
  int krow0 = w * 2 + (lane >> 5);            // K tile row (c=0), +16 for c=1
  const char* kgRow = (const char*)(Kg + (long)(k0base + krow0) * ldk)
                      + (((lane & 31) ^ (krow0 & 7)) * 16);
  int vrow0 = w * 16 + (lane >> 2);           // V tile row (c=0), +128 for c=1
  const char* vgRow = (const char*)(Vg + (long)vrow0 * ldvt + k0base)
                      + (((lane & 3) ^ ((vrow0 >> 1) & 3)) * 16);
  const long kStep = (long)32 * ldk * 2;      // bytes per KV iter
  const long kCOff = (long)16 * ldk * 2;      // c=1 offset
  const long vCOff = (long)128 * ldvt * 2;

  auto stage = [&](int bsel) {
    char* base = pool + bsel * 32768;
#pragma unroll
    for (int c = 0; c < 2; ++c)
      gl16(kgRow + c * kCOff, base + c * 8192 + w * 1024);
#pragma unroll
    for (int c = 0; c < 2; ++c)
      gl16(vgRow + c * vCOff, base + 16384 + c * 8192 + w * 1024);
  };

  const f32x4 zz = {0.f, 0.f, 0.f, 0.f};
  f32x4 accO[16];
#pragma unroll
  for (int i = 0; i < 16; ++i) accO[i] = zz;
  float mrow[4] = {-1e30f, -1e30f, -1e30f, -1e30f};
  float lrow[4] = {0.f, 0.f, 0.f, 0.f};

  stage(0);
  kgRow += kStep; vgRow += 64;

  for (int it = 0; it < NIT; ++it) {
    int cur = it & 1;
    asm volatile("s_waitcnt vmcnt(0)" ::: "memory");
    __syncthreads();
    if (it + 1 < NIT) {           // prefetch next tile, overlaps compute
      stage(cur ^ 1);
      kgRow += kStep; vgRow += 64;
    }
    const char* kls = pool + cur * 32768;
    const char* vls = kls + 16384;

    // S = Q @ K^T (16x32 per wave)
    f32x4 sacc[2];
    __builtin_amdgcn_s_setprio(1);
#pragma unroll
    for (int kc = 0; kc < 2; ++kc) {
      sacc[kc] = zz;
#pragma unroll
      for (int ks = 0; ks < 8; ++ks) {
        s8v bfr = *(const s8v*)&kls[(kc * 16 + l15) * 512 + (((ks * 4 + g) ^ (l15 & 7)) * 16)];
        sacc[kc] = __builtin_amdgcn_mfma_f32_16x16x32_bf16(qf[ks], bfr, sacc[kc], 0, 0, 0);
      }
    }
    __builtin_amdgcn_s_setprio(0);

    // online softmax; rows live in 16-lane groups (row = g*4+r)
#pragma unroll
    for (int kc = 0; kc < 2; ++kc)
#pragma unroll
      for (int r = 0; r < 4; ++r) sacc[kc][r] *= scale;
    float mt[4];
#pragma unroll
    for (int r = 0; r < 4; ++r) mt[r] = fmaxf(sacc[0][r], sacc[1][r]);
#pragma unroll
    for (int o = 1; o < 16; o <<= 1)
#pragma unroll
      for (int r = 0; r < 4; ++r) mt[r] = fmaxf(mt[r], __shfl_xor(mt[r], o));
    // defer-max (T13): only rescale when max grew by > 8
    float dmax = fmaxf(fmaxf(mt[0] - mrow[0], mt[1] - mrow[1]),
                       fmaxf(mt[2] - mrow[2], mt[3] - mrow[3]));
    if (__any(dmax > 8.f)) {
#pragma unroll
      for (int r = 0; r < 4; ++r) {
        float mn = fmaxf(mrow[r], mt[r]);
        float al = __expf(mrow[r] - mn);
        mrow[r] = mn; lrow[r] *= al;
#pragma unroll
        for (int n = 0; n < 16; ++n) accO[n][r] *= al;
      }
    }
    float ps[2][4], lsum[4] = {0.f, 0.f, 0.f, 0.f};
#pragma unroll
    for (int kc = 0; kc < 2; ++kc)
#pragma unroll
      for (int r = 0; r < 4; ++r) {
        float p = __expf(sacc[kc][r] - mrow[r]);
        ps[kc][r] = p; lsum[r] += p;
      }
#pragma unroll
    for (int o = 1; o < 16; o <<= 1)
#pragma unroll
      for (int r = 0; r < 4; ++r) lsum[r] += __shfl_xor(lsum[r], o);
#pragma unroll
    for (int r = 0; r < 4; ++r) lrow[r] += lsum[r];

    // P -> per-wave LDS (bf16)
#pragma unroll
    for (int kc = 0; kc < 2; ++kc)
#pragma unroll
      for (int r = 0; r < 4; ++r)
        *(short*)&Pw[(g * 4 + r) * 64 + ((kc * 32 + l15 * 2) ^ (g << 4))] = f2b(ps[kc][r]);
    s8v pa = *(const s8v*)&Pw[l15 * 64 + ((g * 16) ^ ((l15 >> 2) << 4))];

    // O += P(16x32) @ V(32x256) via Vt in LDS
    __builtin_amdgcn_s_setprio(1);
#pragma unroll
    for (int n = 0; n < 16; ++n) {
      s8v vf = *(const s8v*)&vls[(n * 16 + l15) * 64 + ((g ^ ((l15 >> 1) & 3)) * 16)];
      accO[n] = __builtin_amdgcn_mfma_f32_16x16x32_bf16(pa, vf, accO[n], 0, 0, 0);
    }
    __builtin_amdgcn_s_setprio(0);
  }

  // write partials: O unnormalized bf16, (m,l) fp32
  long prow = (((long)kv * 4 + b) * 8 + h) * 512;
  short* Ob = Opart + prow * 256;
  float* MLb = MLp + prow * 2;
  if (l15 == 0) {
#pragma unroll
    for (int r = 0; r < 4; ++r) {
      int row = q0 + g * 4 + r;
      MLb[row * 2] = mrow[r];
      MLb[row * 2 + 1] = lrow[r];
    }
  }
#pragma unroll
  for (int n = 0; n < 16; ++n)
#pragma unroll
    for (int r = 0; r < 4; ++r)
      Ob[(long)(q0 + g * 4 + r) * 256 + n * 16 + l15] = f2b(accO[n][r]);
}

// ---------------- combine 4 kv partials -> bufO bf16 ----------------
// 512 thr = 2 q-rows per block. out[b][q][h*256+d].
__global__ __launch_bounds__(512) void k_fcomb(
    const short* __restrict__ Op, const float* __restrict__ ML,
    short* __restrict__ O)
{
  int d = threadIdx.x & 255;
  int q = blockIdx.x * 2 + (threadIdx.x >> 8);
  int h = blockIdx.y, b = blockIdx.z;
  const long kvs = 4L * 8 * 512;  // rows per kv slice
  long r0 = ((long)b * 8 + h) * 512 + q;
  float mm[4], ll[4], m = -1e30f;
#pragma unroll
  for (int kv = 0; kv < 4; ++kv) {
    mm[kv] = ML[(kv * kvs + r0) * 2];
    ll[kv] = ML[(kv * kvs + r0) * 2 + 1];
    m = fmaxf(m, mm[kv]);
  }
  float wv[4], lsum = 0.f;
#pragma unroll
  for (int kv = 0; kv < 4; ++kv) { wv[kv] = __expf(mm[kv] - m); lsum += ll[kv] * wv[kv]; }
  float inv = 1.f / lsum, acc = 0.f;
#pragma unroll
  for (int kv = 0; kv < 4; ++kv)
    acc += b2f(Op[(kv * kvs + r0) * 256 + d]) * wv[kv];
  O[(long)b * 1048576 + (long)q * 2048 + h * 256 + d] = f2b(acc * inv);
}

// ---------------- z = LN(sum(Ypart) + bias + res) ----------------
__global__ __launch_bounds__(256) void k_bias_res_ln(
    const float* __restrict__ Yp, int nPart, long pStride,
    const float* __restrict__ bias,
    const float* __restrict__ res, int resMod,
    const float* __restrict__ g, const float* __restrict__ bta,
    float* __restrict__ out, short* __restrict__ out_bf)
{
  __shared__ float red[4];
  int row = blockIdx.x, e = threadIdx.x;
  float v = bias[e] + res[(long)(row % resMod) * 256 + e];
  for (int s = 0; s < nPart; ++s) v += Yp[s * pStride + (long)row * 256 + e];
  float s1 = v;
#pragma unroll
  for (int o = 32; o > 0; o >>= 1) s1 += __shfl_down(s1, o);
  if ((e & 63) == 0) red[e >> 6] = s1;
  __syncthreads();
  float mean = (red[0] + red[1] + red[2] + red[3]) * (1.f / 256.f);
  float d = v - mean;
  __syncthreads();
  float s2 = d * d;
#pragma unroll
  for (int o = 32; o > 0; o >>= 1) s2 += __shfl_down(s2, o);
  if ((e & 63) == 0) red[e >> 6] = s2;
  __syncthreads();
  float var = (red[0] + red[1] + red[2] + red[3]) * (1.f / 256.f);
  float o = g[e] * d * rsqrtf(var + 1e-5f) + bta[e];
  out[(long)row * 256 + e] = o;
  out_bf[(long)row * 256 + e] = f2b(o);
}

// ---------------- zm[b,e] = mean_l z[b,l,e]; cls ----------------
__global__ __launch_bounds__(256) void k_mean(const float* __restrict__ z,
                                              float* __restrict__ zm)
{
  int b = blockIdx.x, e = threadIdx.x;
  float s = 0.f;
  for (int l = 0; l < 512; ++l) s += z[((long)b * 512 + l) * 256 + e];
  zm[b * 256 + e] = s * (1.f / 512.f);
}

__global__ __launch_bounds__(256) void k_cls(const float* __restrict__ zm,
                                             const float* __restrict__ w,
                                             const float* __restrict__ bias,
                                             float* __restrict__ out)
{
  int j = blockIdx.x * 256 + threadIdx.x;
  int b = blockIdx.y;
  if (j >= 1000) return;
  float s = bias[j];
  for (int e = 0; e < 256; ++e) s += zm[b * 256 + e] * w[e * 1000 + j];
  out[b * 1000 + j] = s;
}

extern "C" void kernel_launch(void* const* d_in, const int* in_sizes, int n_in,
                              void* d_out, int out_size, void* d_ws, size_t ws_size,
                              hipStream_t stream)
{
  (void)in_sizes; (void)n_in; (void)out_size; (void)ws_size;
  const float* x       = (const float*)d_in[0];
  const float* conv_w  = (const float*)d_in[1];
  const float* conv_b  = (const float*)d_in[2];
  const float* pos_emb = (const float*)d_in[3];
  const float* latents = (const float*)d_in[4];
  const float* ca_wq   = (const float*)d_in[5];
  const float* ca_wk   = (const float*)d_in[6];
  const float* ca_wv   = (const float*)d_in[7];
  const float* ca_wu   = (const float*)d_in[8];
  const float* ca_bu   = (const float*)d_in[9];
  const float* ca_ln_g = (const float*)d_in[10];
  const float* ca_ln_b = (const float*)d_in[11];
  const float* blk_wq  = (const float*)d_in[12];
  const float* blk_wk  = (const float*)d_in[13];
  const float* blk_wv  = (const float*)d_in[14];
  const float* blk_wu  = (const float*)d_in[15];
  const float* blk_bu  = (const float*)d_in[16];
  const float* blk_ln1_g = (const float*)d_in[17];
  const float* blk_ln1_b = (const float*)d_in[18];
  const float* blk_w1  = (const float*)d_in[19];
  const float* blk_b1  = (const float*)d_in[20];
  const float* blk_w2  = (const float*)d_in[21];
  const float* blk_b2  = (const float*)d_in[22];
  const float* blk_ln2_g = (const float*)d_in[23];
  const float* blk_ln2_b = (const float*)d_in[24];
  const float* cls_w   = (const float*)d_in[25];
  const float* cls_b   = (const float*)d_in[26];
  float* out = (float*)d_out;

  // ---- workspace layout (bf16 as short) ----
  short* wqT_ca = (short*)d_ws;            // 2048x256
  short* wkT_ca = wqT_ca + 524288;         // 2048x256
  short* wuT_ca = wkT_ca + 524288;         // 256x2048
  short* wv_ca  = wuT_ca + 524288;         // 256x2048
  short* lat_bf = wv_ca + 524288;          // 512x256
  short* wqkT   = lat_bf + 131072;         // 4 x (4096x256)
  short* wvT    = wqkT + 4194304;          // 4 x (2048x256)
  short* wuT_b  = wvT + 2097152;           // 4 x (256x2048)
  short* w1T    = wuT_b + 2097152;         // 4 x (1024x256)
  short* w2T    = w1T + 1048576;           // 4 x (256x1024)
  short* tok_bf = w2T + 1048576;           // 4 x 4096x256
  short* tokT   = tok_bf + 4194304;        // 4 x 256x4096
  short* qCA    = tokT + 4194304;          // 512x2048
  short* qtil   = qCA + 1048576;           // 8 x 512x256
  short* MstT   = qtil + 1048576;          // 256x2048
  short* VtB    = MstT + 524288;           // 32 x 256x512
  short* bufO   = VtB + 4194304;           // 4 x 512x2048
  short* h1     = bufO + 4194304;          // 2048x1024
  short* z_bf   = h1 + 2097152;            // 2048x256
  float* z      = (float*)(z_bf + 524288); // 2048x256 fp32
  float* zm     = z + 524288;              // 4x256
  float* Ypart  = zm + 1024;               // 8 x 2048x256 fp32 (split-K partials)
  short* Opart  = (short*)(Ypart + 4194304); // 4 x (4x8x512x256) bf16 kv-partials
  float* MLp    = (float*)(Opart + 16777216); // 4 x (4x8x512x2) fp32
  short* QKb    = tok_bf;                  // alias: 2048x4096 (after CA)

  const float scale = 0.17677669529663687f; // 1/sqrt(32)
  const int BIG = 1 << 30;

  // ---- weight prep (bf16, transposed to NxK) ----
  k_tr<float><<<dim3(64, 8, 1), 256, 0, stream>>>(ca_wq, wqT_ca, 256, 2048, 0, 0);
  k_tr<float><<<dim3(64, 8, 1), 256, 0, stream>>>(ca_wk, wkT_ca, 256, 2048, 0, 0);
  k_tr<float><<<dim3(8, 64, 1), 256, 0, stream>>>(ca_wu, wuT_ca, 2048, 256, 0, 0);
  k_cvt<<<2048, 256, 0, stream>>>(ca_wv, wv_ca);
  k_cvt<<<512, 256, 0, stream>>>(latents, lat_bf);
  k_tr<float><<<dim3(64, 8, 4), 256, 0, stream>>>(blk_wq, wqkT, 256, 2048, 524288, 1048576);
  k_tr<float><<<dim3(64, 8, 4), 256, 0, stream>>>(blk_wk, wqkT + 524288, 256, 2048, 524288, 1048576);
  k_tr<float><<<dim3(64, 8, 4), 256, 0, stream>>>(blk_wv, wvT, 256, 2048, 524288, 524288);
  k_tr<float><<<dim3(8, 64, 4), 256, 0, stream>>>(blk_wu, wuT_b, 2048, 256, 524288, 524288);
  k_tr<float><<<dim3(32, 8, 4), 256, 0, stream>>>(blk_w1, w1T, 256, 1024, 262144, 262144);
  k_tr<float><<<dim3(8, 32, 4), 256, 0, stream>>>(blk_w2, w2T, 1024, 256, 262144, 262144);

  // ---- tokens ----
  k_tokens<<<16384, 256, 0, stream>>>(x, conv_w, conv_b, pos_emb, tok_bf);
  k_tr<__hip_bfloat16><<<dim3(8, 128, 4), 256, 0, stream>>>(
      (const __hip_bfloat16*)tok_bf, tokT, 4096, 256, 1048576, 1048576);

  // ---- cross-attention (W_K folded into Q; W_V*W_U folded into MstT) ----
  k_mgemm<0><<<dim3(16, 4, 1), 256, 0, stream>>>(
      lat_bf, wqT_ca, qCA, nullptr, 256, 256, 256, 2048, 0, 0, 0, 1, BIG, 1, BIG);
  k_mgemm<0><<<dim3(2, 4, 8), 256, 0, stream>>>(
      qCA, wkT_ca, qtil, nullptr, 256, 2048, 256, 256, 256, 65536, 131072, 1, 8, 1, 8);
  k_mgemm<0><<<dim3(2, 2, 8), 256, 0, stream>>>(
      wuT_ca, wv_ca, MstT, nullptr, 256, 2048, 2048, 2048, 256, 256, 256, 1, 8, 1, 8);
  // CA flash: Q=qtilde(h), K=tokens(b), Vt=tokensT(b)
  k_mflash3<<<dim3(16, 8, 4), 512, 0, stream>>>(
      qtil, tok_bf, tokT, Opart, MLp, 4096, 256, 256, 4096,
      131072L, 0L, 0L, 1048576L, 0L, 1048576L, scale);
  k_fcomb<<<dim3(256, 8, 4), 512, 0, stream>>>(Opart, MLp, bufO);
  // Y = bufO(2048x2048) @ MstT^T, split-K x8 -> fp32 partials
  k_mgemm<2><<<dim3(2, 16, 8), 256, 0, stream>>>(
      bufO, MstT, Ypart, nullptr, 256, 2048, 2048, 256, 256, 256, 524288, 1, 8, 1, 8);
  k_bias_res_ln<<<2048, 256, 0, stream>>>(Ypart, 8, 524288L, ca_bu, latents, 512,
                                          ca_ln_g, ca_ln_b, z, z_bf);

  // ---- transformer blocks ----
  for (int d = 0; d < 4; ++d) {
    // [Q|K] = z @ [wq wk]  -> QKb (2048 x 4096) bf16
    k_mgemm<0><<<dim3(32, 16, 1), 256, 0, stream>>>(
        z_bf, wqkT + (long)d * 1048576, QKb, nullptr,
        256, 256, 256, 4096, 0, 0, 0, 1, BIG, 1, BIG);
    // Vt(b,h) = wvT_h @ z_b^T  (256 x 512)
    k_mgemm<0><<<dim3(4, 2, 32), 256, 0, stream>>>(
        wvT + (long)d * 524288, z_bf, VtB, nullptr,
        256, 256, 256, 512, 65536, 131072, 131072, 1, 8, 8, BIG);
    // self flash
    k_mflash3<<<dim3(16, 8, 4), 512, 0, stream>>>(
        QKb, QKb + 2048, VtB, Opart, MLp, 512, 4096, 4096, 512,
        256L, 2097152L, 256L, 2097152L, 131072L, 1048576L, scale);
    k_fcomb<<<dim3(256, 8, 4), 512, 0, stream>>>(Opart, MLp, bufO);
    // Y = bufO @ wu^T, split-K x8 -> fp32 partials
    k_mgemm<2><<<dim3(2, 16, 8), 256, 0, stream>>>(
        bufO, wuT_b + (long)d * 524288, Ypart, nullptr,
        256, 2048, 2048, 256, 256, 256, 524288, 1, 8, 1, 8);
    k_bias_res_ln<<<2048, 256, 0, stream>>>(Ypart, 8, 524288L, blk_bu + d * 256, z, 2048,
        blk_ln1_g + d * 256, blk_ln1_b + d * 256, z, z_bf);
    // h1 = gelu(z @ w1 + b1)
    k_mgemm<1><<<dim3(8, 16, 1), 256, 0, stream>>>(
        z_bf, w1T + (long)d * 262144, h1, blk_b1 + d * 1024,
        256, 256, 256, 1024, 0, 0, 0, 1, BIG, 1, BIG);
    // Y = h1 @ w2, split-K x8 (Ksub=128) -> fp32 partials
    k_mgemm<2><<<dim3(2, 16, 8), 256, 0, stream>>>(
        h1, w2T + (long)d * 262144, Ypart, nullptr,
        128, 1024, 1024, 256, 128, 128, 524288, 1, 8, 1, 8);
    k_bias_res_ln<<<2048, 256, 0, stream>>>(Ypart, 8, 524288L, blk_b2 + d * 256, z, 2048,
        blk_ln2_g + d * 256, blk_ln2_b + d * 256, z, z_bf);
  }

  k_mean<<<4, 256, 0, stream>>>(z, zm);
  k_cls<<<dim3(4, 4), 256, 0, stream>>>(zm, cls_w, cls_b, out);
}

// Round 5
// 655.338 us; speedup vs baseline: 1.0962x; 1.0962x over previous
//
#include <hip/hip_runtime.h>
#include <hip/hip_bf16.h>
#include <math.h>

// Perceiver: B=4,C=3,N=4096,E=256,H=8,FFE=1024,L=512,D=4,NCLS=1000,HS=2048
// bf16 MFMA everywhere GEMM-shaped; fp32 accum; fp32 LN/residual spine.

typedef __attribute__((ext_vector_type(8))) short s8v;   // 8 bf16 = 4 VGPR
typedef __attribute__((ext_vector_type(4))) float f32x4; // MFMA accum

__device__ __forceinline__ short f2b(float f) {
  union { float f; unsigned u; } a; a.f = f;
  unsigned r = a.u + 0x7fff + ((a.u >> 16) & 1);
  return (short)(r >> 16);
}
__device__ __forceinline__ float b2f(short s) {
  union { unsigned u; float f; } a; a.u = ((unsigned)(unsigned short)s) << 16;
  return a.f;
}

// async global->LDS, 16B per lane; LDS dest = uniform base + lane*16
__device__ __forceinline__ void gl16(const void* gp, void* lp) {
  __builtin_amdgcn_global_load_lds(
      (const __attribute__((address_space(1))) unsigned int*)gp,
      (__attribute__((address_space(3))) unsigned int*)lp, 16, 0, 0);
}

// ---------------- tokens(bf16) = conv1x1(x) + bias + pos ----------------
__global__ __launch_bounds__(256) void k_tokens(
    const float* __restrict__ x, const float* __restrict__ cw,
    const float* __restrict__ cb, const float* __restrict__ pe,
    short* __restrict__ tok)
{
  int idx = blockIdx.x * 256 + threadIdx.x;   // B*N*E
  int e = idx & 255;
  int n = (idx >> 8) & 4095;
  int b = idx >> 20;
  float s = cb[e] + pe[n * 256 + e];
#pragma unroll
  for (int c = 0; c < 3; ++c)
    s += x[b * 12288 + c * 4096 + n] * cw[e * 3 + c];
  tok[idx] = f2b(s);
}

// ---------------- transpose: in (R,C) bf16 -> out bf16 (C,R) ----
template<typename TI>
__global__ __launch_bounds__(256) void k_tr(
    const TI* __restrict__ in, short* __restrict__ out,
    int R, int C, long sIn, long sOut)
{
  __shared__ float t[32][33];
  const TI* ib = in + (long)blockIdx.z * sIn;
  short* ob = out + (long)blockIdx.z * sOut;
  int c0 = blockIdx.x * 32, r0 = blockIdx.y * 32;
  int tx = threadIdx.x & 31, ty = threadIdx.x >> 5; // 32 x 8
#pragma unroll
  for (int i = 0; i < 4; ++i)
    t[ty * 4 + i][tx] = (float)ib[(long)(r0 + ty * 4 + i) * C + c0 + tx];
  __syncthreads();
#pragma unroll
  for (int i = 0; i < 4; ++i)
    ob[(long)(c0 + ty * 4 + i) * R + r0 + tx] = f2b(t[tx][ty * 4 + i]);
}

// ---------------- batched weight prep: transposes + flat converts --------
struct TrJob {
  const float* src; short* dst;
  int R, C; long sIn, sOut;
  int mode, tilesPerZ, z, tileBase;
};
struct TrJobs { TrJob j[11]; };

__global__ __launch_bounds__(256) void k_trbatch(TrJobs jb, int njobs)
{
  __shared__ float t[32][33];
  int tb = blockIdx.x, ji = 0;
#pragma unroll
  for (int k = 1; k < 11; ++k)
    if (k < njobs && tb >= jb.j[k].tileBase) ji = k;
  TrJob J = jb.j[ji];
  int local = tb - J.tileBase;
  if (J.mode == 1) {          // flat fp32 -> bf16
    long o = (long)local * 8192 + threadIdx.x;
#pragma unroll
    for (int k = 0; k < 32; ++k) J.dst[o + k * 256] = f2b(J.src[o + k * 256]);
    return;
  }
  int zi = local / J.tilesPerZ, ti = local - zi * J.tilesPerZ;
  int ntx = J.C >> 5;
  int tx = ti % ntx, ty = ti / ntx;
  const float* ib = J.src + (long)zi * J.sIn;
  short* ob = J.dst + (long)zi * J.sOut;
  int c0 = tx * 32, r0 = ty * 32;
  int lx = threadIdx.x & 31, ly = threadIdx.x >> 5;
#pragma unroll
  for (int i = 0; i < 4; ++i)
    t[ly * 4 + i][lx] = ib[(long)(r0 + ly * 4 + i) * J.C + c0 + lx];
  __syncthreads();
#pragma unroll
  for (int i = 0; i < 4; ++i)
    ob[(long)(c0 + ly * 4 + i) * J.R + r0 + lx] = f2b(t[lx][ly * 4 + i]);
}

// ---------------- bf16 MFMA BT-GEMM: C = A(MxK) @ Bt(NxK)^T ----------------
// 128x128 tile, BK=32, 256 thr. Prefetch pipeline. Requires K % 64 == 0.
// EPI: 0 = bf16 out, 1 = bias+exact-gelu bf16 out, 2 = fp32 out (partials).
template<int EPI>
__global__ __launch_bounds__(256) void k_mgemm(
    const short* __restrict__ A, const short* __restrict__ Bt,
    void* __restrict__ Cv, const float* __restrict__ bias,
    int K, int lda, int ldb, int ldc,
    long sA, long sB, long sC, int zdA, int zmA, int zdB, int zmB)
{
  __shared__ char As[8192];
  __shared__ char Bs[8192];
  int z = blockIdx.z;
  const short* Ab = A + ((long)((z / zdA) % zmA)) * sA;
  const short* Bb = Bt + ((long)((z / zdB) % zmB)) * sB;
  int t = threadIdx.x;
  int lane = t & 63, w = t >> 6;
  int wr = w >> 1, wc = w & 1;
  int g = lane >> 4, l15 = lane & 15;
  long row0 = (long)blockIdx.y * 128, col0 = (long)blockIdx.x * 128;
  const f32x4 zz = {0.f, 0.f, 0.f, 0.f};
  f32x4 acc[4][4];
#pragma unroll
  for (int m = 0; m < 4; ++m)
#pragma unroll
    for (int n = 0; n < 4; ++n) acc[m][n] = zz;

  auto mload = [&](s8v* aa, s8v* bb, int kk) {
#pragma unroll
    for (int i = 0; i < 2; ++i) {
      int r = i * 64 + (t >> 2), c = t & 3;
      aa[i] = *(const s8v*)&Ab[(row0 + r) * (long)lda + kk + c * 8];
      bb[i] = *(const s8v*)&Bb[(col0 + r) * (long)ldb + kk + c * 8];
    }
  };
  auto mstore = [&](s8v* aa, s8v* bb) {
#pragma unroll
    for (int i = 0; i < 2; ++i) {
      int r = i * 64 + (t >> 2), c = t & 3;
      int off = (r * 64 + c * 16) ^ ((r & 7) << 4);
      *(s8v*)&As[off] = aa[i];
      *(s8v*)&Bs[off] = bb[i];
    }
  };
  auto mcomp = [&]() {
    s8v af[4], bfr[4];
#pragma unroll
    for (int m = 0; m < 4; ++m) {
      int r = wr * 64 + m * 16 + l15;
      af[m] = *(const s8v*)&As[(r * 64 + g * 16) ^ ((r & 7) << 4)];
    }
#pragma unroll
    for (int n = 0; n < 4; ++n) {
      int r = wc * 64 + n * 16 + l15;
      bfr[n] = *(const s8v*)&Bs[(r * 64 + g * 16) ^ ((r & 7) << 4)];
    }
#pragma unroll
    for (int m = 0; m < 4; ++m)
#pragma unroll
      for (int n = 0; n < 4; ++n)
        acc[m][n] = __builtin_amdgcn_mfma_f32_16x16x32_bf16(af[m], bfr[n], acc[m][n], 0, 0, 0);
  };

  s8v a0[2], b0[2], a1[2], b1[2];
  mload(a0, b0, 0);
  for (int k0 = 0; k0 < K; k0 += 64) {
    __syncthreads(); mstore(a0, b0); __syncthreads();
    mload(a1, b1, k0 + 32);
    mcomp();
    __syncthreads(); mstore(a1, b1); __syncthreads();
    if (k0 + 64 < K) mload(a0, b0, k0 + 64);
    mcomp();
  }

  long zo = (long)z * sC;
#pragma unroll
  for (int m = 0; m < 4; ++m)
#pragma unroll
    for (int n = 0; n < 4; ++n)
#pragma unroll
      for (int r = 0; r < 4; ++r) {
        long rr = row0 + wr * 64 + m * 16 + g * 4 + r;
        long cc = col0 + wc * 64 + n * 16 + l15;
        float v = acc[m][n][r];
        if (EPI == 1) {
          v += bias[cc];
          v = 0.5f * v * (1.f + erff(v * 0.70710678118654752f));
        }
        if (EPI == 2)
          ((float*)Cv)[zo + rr * ldc + cc] = v;
        else
          ((short*)Cv)[zo + rr * ldc + cc] = f2b(v);
      }
}

// ---------------- MFMA flash attention v4 (head dim 256) ----------------
// 512 thr = 8 waves, each wave owns 32 q-rows (2x16 subtiles) so every
// K/V LDS fragment read feeds 2 MFMAs (halves LDS bytes per FLOP).
// kv-split x4 across blocks; unnormalized bf16 O + fp32 (m,l) partials.
// LDS 80KB; VGPR ~250 -> 2 waves/SIMD, 1 block/CU.
__global__ __launch_bounds__(512, 2) void k_mflash4(
    const short* __restrict__ Qp, const short* __restrict__ Kp,
    const short* __restrict__ Vtp, short* __restrict__ Opart,
    float* __restrict__ MLp,
    int nk, int ldq, int ldk, int ldvt,
    long qh, long qb, long kh, long kb, long vh, long vb, float scale)
{
  __shared__ char pool[81920]; // buf0 K@0 V@16K, buf1 K@32K V@48K, P@64K(16K)
  int t = threadIdx.x, lane = t & 63, w = t >> 6;
  int g = lane >> 4, l15 = lane & 15;
  int h = blockIdx.y, b = blockIdx.z;
  int kv = blockIdx.x & 3, qblk = blockIdx.x >> 2;
  const short* Q  = Qp  + (long)h * qh + (long)b * qb;
  const short* Kg = Kp  + (long)h * kh + (long)b * kb;
  const short* Vg = Vtp + (long)h * vh + (long)b * vb;
  char* Pw = pool + 65536 + w * 2048;
  int q0 = qblk * 256 + w * 32;
  int nkq = nk >> 2;          // keys per block
  int NIT = nkq >> 5;         // KVBLK = 32
  int k0base = kv * nkq;

  // Q fragments, 2 subtiles: A-frag row=l15, k = ks*32 + g*8
  s8v qf[2][8];
#pragma unroll
  for (int s = 0; s < 2; ++s) {
    const short* Qrow = Q + (long)(q0 + s * 16 + l15) * ldq + g * 8;
#pragma unroll
    for (int ks = 0; ks < 8; ++ks) qf[s][ks] = *(const s8v*)(Qrow + ks * 32);
  }

  // staging sources (linear LDS dest + inverse-swizzled global source)
  int krow0 = w * 2 + (lane >> 5);
  const char* kgRow = (const char*)(Kg + (long)(k0base + krow0) * ldk)
                      + (((lane & 31) ^ (krow0 & 7)) * 16);
  int vrow0 = w * 16 + (lane >> 2);
  const char* vgRow = (const char*)(Vg + (long)vrow0 * ldvt + k0base)
                      + (((lane & 3) ^ ((vrow0 >> 1) & 3)) * 16);
  const long kStep = (long)32 * ldk * 2;
  const long kCOff = (long)16 * ldk * 2;
  const long vCOff = (long)128 * ldvt * 2;

  auto stage = [&](int bsel) {
    char* base = pool + bsel * 32768;
#pragma unroll
    for (int c = 0; c < 2; ++c)
      gl16(kgRow + c * kCOff, base + c * 8192 + w * 1024);
#pragma unroll
    for (int c = 0; c < 2; ++c)
      gl16(vgRow + c * vCOff, base + 16384 + c * 8192 + w * 1024);
  };

  const f32x4 zz = {0.f, 0.f, 0.f, 0.f};
  f32x4 accO[2][16];
#pragma unroll
  for (int s = 0; s < 2; ++s)
#pragma unroll
    for (int i = 0; i < 16; ++i) accO[s][i] = zz;
  float mrow[2][4] = {{-1e30f, -1e30f, -1e30f, -1e30f},
                      {-1e30f, -1e30f, -1e30f, -1e30f}};
  float lrow[2][4] = {{0.f, 0.f, 0.f, 0.f}, {0.f, 0.f, 0.f, 0.f}};

  stage(0);
  kgRow += kStep; vgRow += 64;

  for (int it = 0; it < NIT; ++it) {
    int cur = it & 1;
    asm volatile("s_waitcnt vmcnt(0)" ::: "memory");
    __syncthreads();
    if (it + 1 < NIT) {           // prefetch next tile, overlaps compute
      stage(cur ^ 1);
      kgRow += kStep; vgRow += 64;
    }
    const char* kls = pool + cur * 32768;
    const char* vls = kls + 16384;

    // S = Q @ K^T (2 subtiles x 16x32): each K-frag read used twice
    f32x4 sacc[2][2];
    __builtin_amdgcn_s_setprio(1);
#pragma unroll
    for (int kc = 0; kc < 2; ++kc) {
      sacc[0][kc] = zz; sacc[1][kc] = zz;
#pragma unroll
      for (int ks = 0; ks < 8; ++ks) {
        s8v bfr = *(const s8v*)&kls[(kc * 16 + l15) * 512 + (((ks * 4 + g) ^ (l15 & 7)) * 16)];
        sacc[0][kc] = __builtin_amdgcn_mfma_f32_16x16x32_bf16(qf[0][ks], bfr, sacc[0][kc], 0, 0, 0);
        sacc[1][kc] = __builtin_amdgcn_mfma_f32_16x16x32_bf16(qf[1][ks], bfr, sacc[1][kc], 0, 0, 0);
      }
    }
    __builtin_amdgcn_s_setprio(0);

    // online softmax per subtile; rows live in 16-lane groups (row = g*4+r)
#pragma unroll
    for (int s = 0; s < 2; ++s) {
#pragma unroll
      for (int kc = 0; kc < 2; ++kc)
#pragma unroll
        for (int r = 0; r < 4; ++r) sacc[s][kc][r] *= scale;
      float mt[4];
#pragma unroll
      for (int r = 0; r < 4; ++r) mt[r] = fmaxf(sacc[s][0][r], sacc[s][1][r]);
#pragma unroll
      for (int o = 1; o < 16; o <<= 1)
#pragma unroll
        for (int r = 0; r < 4; ++r) mt[r] = fmaxf(mt[r], __shfl_xor(mt[r], o));
      // defer-max (T13): only rescale when max grew by > 8
      float dmax = fmaxf(fmaxf(mt[0] - mrow[s][0], mt[1] - mrow[s][1]),
                         fmaxf(mt[2] - mrow[s][2], mt[3] - mrow[s][3]));
      if (__any(dmax > 8.f)) {
#pragma unroll
        for (int r = 0; r < 4; ++r) {
          float mn = fmaxf(mrow[s][r], mt[r]);
          float al = __expf(mrow[s][r] - mn);
          mrow[s][r] = mn; lrow[s][r] *= al;
#pragma unroll
          for (int n = 0; n < 16; ++n) accO[s][n][r] *= al;
        }
      }
      float lsum[4] = {0.f, 0.f, 0.f, 0.f};
#pragma unroll
      for (int kc = 0; kc < 2; ++kc)
#pragma unroll
        for (int r = 0; r < 4; ++r) {
          float p = __expf(sacc[s][kc][r] - mrow[s][r]);
          lsum[r] += p;
          *(short*)&Pw[s * 1024 + (g * 4 + r) * 64 + ((kc * 32 + l15 * 2) ^ (g << 4))] = f2b(p);
        }
#pragma unroll
      for (int o = 1; o < 16; o <<= 1)
#pragma unroll
        for (int r = 0; r < 4; ++r) lsum[r] += __shfl_xor(lsum[r], o);
#pragma unroll
      for (int r = 0; r < 4; ++r) lrow[s][r] += lsum[r];
    }
    s8v pa0 = *(const s8v*)&Pw[l15 * 64 + ((g * 16) ^ ((l15 >> 2) << 4))];
    s8v pa1 = *(const s8v*)&Pw[1024 + l15 * 64 + ((g * 16) ^ ((l15 >> 2) << 4))];

    // O += P(16x32) @ V(32x256): each V-frag read used twice
    __builtin_amdgcn_s_setprio(1);
#pragma unroll
    for (int n = 0; n < 16; ++n) {
      s8v vf = *(const s8v*)&vls[(n * 16 + l15) * 64 + ((g ^ ((l15 >> 1) & 3)) * 16)];
      accO[0][n] = __builtin_amdgcn_mfma_f32_16x16x32_bf16(pa0, vf, accO[0][n], 0, 0, 0);
      accO[1][n] = __builtin_amdgcn_mfma_f32_16x16x32_bf16(pa1, vf, accO[1][n], 0, 0, 0);
    }
    __builtin_amdgcn_s_setprio(0);
  }

  // write partials: O unnormalized bf16, (m,l) fp32
  long prow = (((long)kv * 4 + b) * 8 + h) * 512;
  short* Ob = Opart + prow * 256;
  float* MLb = MLp + prow * 2;
#pragma unroll
  for (int s = 0; s < 2; ++s) {
    if (l15 == 0) {
#pragma unroll
      for (int r = 0; r < 4; ++r) {
        int row = q0 + s * 16 + g * 4 + r;
        MLb[row * 2] = mrow[s][r];
        MLb[row * 2 + 1] = lrow[s][r];
      }
    }
#pragma unroll
    for (int n = 0; n < 16; ++n)
#pragma unroll
      for (int r = 0; r < 4; ++r)
        Ob[(long)(q0 + s * 16 + g * 4 + r) * 256 + n * 16 + l15] = f2b(accO[s][n][r]);
  }
}

// ---------------- combine 4 kv partials -> bufO bf16 ----------------
__global__ __launch_bounds__(512) void k_fcomb(
    const short* __restrict__ Op, const float* __restrict__ ML,
    short* __restrict__ O)
{
  int d = threadIdx.x & 255;
  int q = blockIdx.x * 2 + (threadIdx.x >> 8);
  int h = blockIdx.y, b = blockIdx.z;
  const long kvs = 4L * 8 * 512;  // rows per kv slice
  long r0 = ((long)b * 8 + h) * 512 + q;
  float mm[4], ll[4], m = -1e30f;
#pragma unroll
  for (int kv = 0; kv < 4; ++kv) {
    mm[kv] = ML[(kv * kvs + r0) * 2];
    ll[kv] = ML[(kv * kvs + r0) * 2 + 1];
    m = fmaxf(m, mm[kv]);
  }
  float wv[4], lsum = 0.f;
#pragma unroll
  for (int kv = 0; kv < 4; ++kv) { wv[kv] = __expf(mm[kv] - m); lsum += ll[kv] * wv[kv]; }
  float inv = 1.f / lsum, acc = 0.f;
#pragma unroll
  for (int kv = 0; kv < 4; ++kv)
    acc += b2f(Op[(kv * kvs + r0) * 256 + d]) * wv[kv];
  O[(long)b * 1048576 + (long)q * 2048 + h * 256 + d] = f2b(acc * inv);
}

// ---------------- z = LN(sum(Ypart) + bias + res) ----------------
__global__ __launch_bounds__(256) void k_bias_res_ln(
    const float* __restrict__ Yp, int nPart, long pStride,
    const float* __restrict__ bias,
    const float* __restrict__ res, int resMod,
    const float* __restrict__ g, const float* __restrict__ bta,
    float* __restrict__ out, short* __restrict__ out_bf)
{
  __shared__ float red[4];
  int row = blockIdx.x, e = threadIdx.x;
  float v = bias[e] + res[(long)(row % resMod) * 256 + e];
  for (int s = 0; s < nPart; ++s) v += Yp[s * pStride + (long)row * 256 + e];
  float s1 = v;
#pragma unroll
  for (int o = 32; o > 0; o >>= 1) s1 += __shfl_down(s1, o);
  if ((e & 63) == 0) red[e >> 6] = s1;
  __syncthreads();
  float mean = (red[0] + red[1] + red[2] + red[3]) * (1.f / 256.f);
  float d = v - mean;
  __syncthreads();
  float s2 = d * d;
#pragma unroll
  for (int o = 32; o > 0; o >>= 1) s2 += __shfl_down(s2, o);
  if ((e & 63) == 0) red[e >> 6] = s2;
  __syncthreads();
  float var = (red[0] + red[1] + red[2] + red[3]) * (1.f / 256.f);
  float o = g[e] * d * rsqrtf(var + 1e-5f) + bta[e];
  out[(long)row * 256 + e] = o;
  out_bf[(long)row * 256 + e] = f2b(o);
}

// ---------------- fused mean-over-latents + classifier ----------------
__global__ __launch_bounds__(256) void k_meancls(
    const float* __restrict__ z, const float* __restrict__ w,
    const float* __restrict__ bias, float* __restrict__ out)
{
  __shared__ float zms[256];
  int b = blockIdx.y, e = threadIdx.x;
  float s = 0.f;
  for (int l = 0; l < 512; ++l) s += z[((long)b * 512 + l) * 256 + e];
  zms[e] = s * (1.f / 512.f);
  __syncthreads();
  int j = blockIdx.x * 256 + e;
  if (j >= 1000) return;
  float acc = bias[j];
  for (int e2 = 0; e2 < 256; ++e2) acc += zms[e2] * w[e2 * 1000 + j];
  out[b * 1000 + j] = acc;
}

extern "C" void kernel_launch(void* const* d_in, const int* in_sizes, int n_in,
                              void* d_out, int out_size, void* d_ws, size_t ws_size,
                              hipStream_t stream)
{
  (void)in_sizes; (void)n_in; (void)out_size; (void)ws_size;
  const float* x       = (const float*)d_in[0];
  const float* conv_w  = (const float*)d_in[1];
  const float* conv_b  = (const float*)d_in[2];
  const float* pos_emb = (const float*)d_in[3];
  const float* latents = (const float*)d_in[4];
  const float* ca_wq   = (const float*)d_in[5];
  const float* ca_wk   = (const float*)d_in[6];
  const float* ca_wv   = (const float*)d_in[7];
  const float* ca_wu   = (const float*)d_in[8];
  const float* ca_bu   = (const float*)d_in[9];
  const float* ca_ln_g = (const float*)d_in[10];
  const float* ca_ln_b = (const float*)d_in[11];
  const float* blk_wq  = (const float*)d_in[12];
  const float* blk_wk  = (const float*)d_in[13];
  const float* blk_wv  = (const float*)d_in[14];
  const float* blk_wu  = (const float*)d_in[15];
  const float* blk_bu  = (const float*)d_in[16];
  const float* blk_ln1_g = (const float*)d_in[17];
  const float* blk_ln1_b = (const float*)d_in[18];
  const float* blk_w1  = (const float*)d_in[19];
  const float* blk_b1  = (const float*)d_in[20];
  const float* blk_w2  = (const float*)d_in[21];
  const float* blk_b2  = (const float*)d_in[22];
  const float* blk_ln2_g = (const float*)d_in[23];
  const float* blk_ln2_b = (const float*)d_in[24];
  const float* cls_w   = (const float*)d_in[25];
  const float* cls_b   = (const float*)d_in[26];
  float* out = (float*)d_out;

  // ---- workspace layout (bf16 as short) ----
  short* wqT_ca = (short*)d_ws;            // 2048x256
  short* wkT_ca = wqT_ca + 524288;         // 2048x256
  short* wuT_ca = wkT_ca + 524288;         // 256x2048
  short* wv_ca  = wuT_ca + 524288;         // 256x2048
  short* lat_bf = wv_ca + 524288;          // 512x256
  short* wqkT   = lat_bf + 131072;         // 4 x (4096x256)
  short* wvT    = wqkT + 4194304;          // 4 x (2048x256)
  short* wuT_b  = wvT + 2097152;           // 4 x (256x2048)
  short* w1T    = wuT_b + 2097152;         // 4 x (1024x256)
  short* w2T    = w1T + 1048576;           // 4 x (256x1024)
  short* tok_bf = w2T + 1048576;           // 4 x 4096x256
  short* tokT   = tok_bf + 4194304;        // 4 x 256x4096
  short* qCA    = tokT + 4194304;          // 512x2048
  short* qtil   = qCA + 1048576;           // 8 x 512x256
  short* MstT   = qtil + 1048576;          // 256x2048
  short* VtB    = MstT + 524288;           // 32 x 256x512
  short* bufO   = VtB + 4194304;           // 4 x 512x2048
  short* h1     = bufO + 4194304;          // 2048x1024
  short* z_bf   = h1 + 2097152;            // 2048x256
  float* z      = (float*)(z_bf + 524288); // 2048x256 fp32
  float* zm     = z + 524288;              // 4x256 (unused now)
  float* Ypart  = zm + 1024;               // 8 x 2048x256 fp32 (split-K partials)
  short* Opart  = (short*)(Ypart + 4194304); // 4 x (4x8x512x256) bf16 kv-partials
  float* MLp    = (float*)(Opart + 16777216); // 4 x (4x8x512x2) fp32
  short* QKb    = tok_bf;                  // alias: 2048x4096 (after CA)

  const float scale = 0.17677669529663687f; // 1/sqrt(32)
  const int BIG = 1 << 30;

  // ---- weight prep: one batched dispatch ----
  TrJobs JB; int nj = 0, base = 0;
  auto addT = [&](const float* s, short* d, int R, int C, long sIn, long sOut, int zc) {
    int tpz = (C >> 5) * (R >> 5);
    JB.j[nj] = {s, d, R, C, sIn, sOut, 0, tpz, zc, base};
    base += tpz * zc; ++nj;
  };
  auto addC = [&](const float* s, short* d, int nelem) {
    int tpz = nelem >> 13;
    JB.j[nj] = {s, d, 0, 0, 0, 0, 1, tpz, 1, base};
    base += tpz; ++nj;
  };
  addT(ca_wq, wqT_ca, 256, 2048, 0, 0, 1);
  addT(ca_wk, wkT_ca, 256, 2048, 0, 0, 1);
  addT(ca_wu, wuT_ca, 2048, 256, 0, 0, 1);
  addT(blk_wq, wqkT, 256, 2048, 524288, 1048576, 4);
  addT(blk_wk, wqkT + 524288, 256, 2048, 524288, 1048576, 4);
  addT(blk_wv, wvT, 256, 2048, 524288, 524288, 4);
  addT(blk_wu, wuT_b, 2048, 256, 524288, 524288, 4);
  addT(blk_w1, w1T, 256, 1024, 262144, 262144, 4);
  addT(blk_w2, w2T, 1024, 256, 262144, 262144, 4);
  addC(ca_wv, wv_ca, 524288);
  addC(latents, lat_bf, 131072);
  k_trbatch<<<base, 256, 0, stream>>>(JB, nj);

  // ---- tokens ----
  k_tokens<<<16384, 256, 0, stream>>>(x, conv_w, conv_b, pos_emb, tok_bf);
  k_tr<__hip_bfloat16><<<dim3(8, 128, 4), 256, 0, stream>>>(
      (const __hip_bfloat16*)tok_bf, tokT, 4096, 256, 1048576, 1048576);

  // ---- cross-attention (W_K folded into Q; W_V*W_U folded into MstT) ----
  k_mgemm<0><<<dim3(16, 4, 1), 256, 0, stream>>>(
      lat_bf, wqT_ca, qCA, nullptr, 256, 256, 256, 2048, 0, 0, 0, 1, BIG, 1, BIG);
  k_mgemm<0><<<dim3(2, 4, 8), 256, 0, stream>>>(
      qCA, wkT_ca, qtil, nullptr, 256, 2048, 256, 256, 256, 65536, 131072, 1, 8, 1, 8);
  k_mgemm<0><<<dim3(2, 2, 8), 256, 0, stream>>>(
      wuT_ca, wv_ca, MstT, nullptr, 256, 2048, 2048, 2048, 256, 256, 256, 1, 8, 1, 8);
  // CA flash: Q=qtilde(h), K=tokens(b), Vt=tokensT(b)
  k_mflash4<<<dim3(8, 8, 4), 512, 0, stream>>>(
      qtil, tok_bf, tokT, Opart, MLp, 4096, 256, 256, 4096,
      131072L, 0L, 0L, 1048576L, 0L, 1048576L, scale);
  k_fcomb<<<dim3(256, 8, 4), 512, 0, stream>>>(Opart, MLp, bufO);
  // Y = bufO(2048x2048) @ MstT^T, split-K x8 -> fp32 partials
  k_mgemm<2><<<dim3(2, 16, 8), 256, 0, stream>>>(
      bufO, MstT, Ypart, nullptr, 256, 2048, 2048, 256, 256, 256, 524288, 1, 8, 1, 8);
  k_bias_res_ln<<<2048, 256, 0, stream>>>(Ypart, 8, 524288L, ca_bu, latents, 512,
                                          ca_ln_g, ca_ln_b, z, z_bf);

  // ---- transformer blocks ----
  for (int d = 0; d < 4; ++d) {
    // [Q|K] = z @ [wq wk]  -> QKb (2048 x 4096) bf16
    k_mgemm<0><<<dim3(32, 16, 1), 256, 0, stream>>>(
        z_bf, wqkT + (long)d * 1048576, QKb, nullptr,
        256, 256, 256, 4096, 0, 0, 0, 1, BIG, 1, BIG);
    // Vt(b,h) = wvT_h @ z_b^T  (256 x 512)
    k_mgemm<0><<<dim3(4, 2, 32), 256, 0, stream>>>(
        wvT + (long)d * 524288, z_bf, VtB, nullptr,
        256, 256, 256, 512, 65536, 131072, 131072, 1, 8, 8, BIG);
    // self flash
    k_mflash4<<<dim3(8, 8, 4), 512, 0, stream>>>(
        QKb, QKb + 2048, VtB, Opart, MLp, 512, 4096, 4096, 512,
        256L, 2097152L, 256L, 2097152L, 131072L, 1048576L, scale);
    k_fcomb<<<dim3(256, 8, 4), 512, 0, stream>>>(Opart, MLp, bufO);
    // Y = bufO @ wu^T, split-K x8 -> fp32 partials
    k_mgemm<2><<<dim3(2, 16, 8), 256, 0, stream>>>(
        bufO, wuT_b + (long)d * 524288, Ypart, nullptr,
        256, 2048, 2048, 256, 256, 256, 524288, 1, 8, 1, 8);
    k_bias_res_ln<<<2048, 256, 0, stream>>>(Ypart, 8, 524288L, blk_bu + d * 256, z, 2048,
        blk_ln1_g + d * 256, blk_ln1_b + d * 256, z, z_bf);
    // h1 = gelu(z @ w1 + b1)
    k_mgemm<1><<<dim3(8, 16, 1), 256, 0, stream>>>(
        z_bf, w1T + (long)d * 262144, h1, blk_b1 + d * 1024,
        256, 256, 256, 1024, 0, 0, 0, 1, BIG, 1, BIG);
    // Y = h1 @ w2, split-K x8 (Ksub=128) -> fp32 partials
    k_mgemm<2><<<dim3(2, 16, 8), 256, 0, stream>>>(
        h1, w2T + (long)d * 262144, Ypart, nullptr,
        128, 1024, 1024, 256, 128, 128, 524288, 1, 8, 1, 8);
    k_bias_res_ln<<<2048, 256, 0, stream>>>(Ypart, 8, 524288L, blk_b2 + d * 256, z, 2048,
        blk_ln2_g + d * 256, blk_ln2_b + d * 256, z, z_bf);
  }

  k_meancls<<<dim3(4, 4), 256, 0, stream>>>(z, cls_w, cls_b, out);
}

// Round 6
// 635.662 us; speedup vs baseline: 1.1301x; 1.0310x over previous
//
#include <hip/hip_runtime.h>
#include <hip/hip_bf16.h>
#include <math.h>

// Perceiver: B=4,C=3,N=4096,E=256,H=8,FFE=1024,L=512,D=4,NCLS=1000,HS=2048
// bf16 MFMA everywhere GEMM-shaped; fp32 accum; fp32 LN/residual spine.

typedef __attribute__((ext_vector_type(8))) short s8v;    // 8 bf16 = 4 VGPR
typedef __attribute__((ext_vector_type(4))) float f32x4;  // 16x16 MFMA accum
typedef __attribute__((ext_vector_type(16))) float f32x16;// 32x32 MFMA accum
typedef __attribute__((ext_vector_type(4))) unsigned u32x4;

__device__ __forceinline__ short f2b(float f) {
  union { float f; unsigned u; } a; a.f = f;
  unsigned r = a.u + 0x7fff + ((a.u >> 16) & 1);
  return (short)(r >> 16);
}
__device__ __forceinline__ float b2f(short s) {
  union { unsigned u; float f; } a; a.u = ((unsigned)(unsigned short)s) << 16;
  return a.f;
}
__device__ __forceinline__ unsigned cvtpk(float lo, float hi) {
  unsigned r;
  asm("v_cvt_pk_bf16_f32 %0, %1, %2" : "=v"(r) : "v"(lo), "v"(hi));
  return r;
}

// async global->LDS, 16B per lane; LDS dest = uniform base + lane*16
__device__ __forceinline__ void gl16(const void* gp, void* lp) {
  __builtin_amdgcn_global_load_lds(
      (const __attribute__((address_space(1))) unsigned int*)gp,
      (__attribute__((address_space(3))) unsigned int*)lp, 16, 0, 0);
}

// ---------------- tokens(bf16) = conv1x1(x) + bias + pos ----------------
__global__ __launch_bounds__(256) void k_tokens(
    const float* __restrict__ x, const float* __restrict__ cw,
    const float* __restrict__ cb, const float* __restrict__ pe,
    short* __restrict__ tok)
{
  int idx = blockIdx.x * 256 + threadIdx.x;   // B*N*E
  int e = idx & 255;
  int n = (idx >> 8) & 4095;
  int b = idx >> 20;
  float s = cb[e] + pe[n * 256 + e];
#pragma unroll
  for (int c = 0; c < 3; ++c)
    s += x[b * 12288 + c * 4096 + n] * cw[e * 3 + c];
  tok[idx] = f2b(s);
}

// ---------------- transpose: in (R,C) bf16 -> out bf16 (C,R) ----
template<typename TI>
__global__ __launch_bounds__(256) void k_tr(
    const TI* __restrict__ in, short* __restrict__ out,
    int R, int C, long sIn, long sOut)
{
  __shared__ float t[32][33];
  const TI* ib = in + (long)blockIdx.z * sIn;
  short* ob = out + (long)blockIdx.z * sOut;
  int c0 = blockIdx.x * 32, r0 = blockIdx.y * 32;
  int tx = threadIdx.x & 31, ty = threadIdx.x >> 5; // 32 x 8
#pragma unroll
  for (int i = 0; i < 4; ++i)
    t[ty * 4 + i][tx] = (float)ib[(long)(r0 + ty * 4 + i) * C + c0 + tx];
  __syncthreads();
#pragma unroll
  for (int i = 0; i < 4; ++i)
    ob[(long)(c0 + ty * 4 + i) * R + r0 + tx] = f2b(t[tx][ty * 4 + i]);
}

// ---------------- batched weight prep: transposes + flat converts --------
struct TrJob {
  const float* src; short* dst;
  int R, C; long sIn, sOut;
  int mode, tilesPerZ, z, tileBase;
  float scale;
};
struct TrJobs { TrJob j[11]; };

__global__ __launch_bounds__(256) void k_trbatch(TrJobs jb, int njobs)
{
  __shared__ float t[32][33];
  int tb = blockIdx.x, ji = 0;
#pragma unroll
  for (int k = 1; k < 11; ++k)
    if (k < njobs && tb >= jb.j[k].tileBase) ji = k;
  TrJob J = jb.j[ji];
  int local = tb - J.tileBase;
  if (J.mode == 1) {          // flat fp32 -> bf16
    long o = (long)local * 8192 + threadIdx.x;
#pragma unroll
    for (int k = 0; k < 32; ++k)
      J.dst[o + k * 256] = f2b(J.src[o + k * 256] * J.scale);
    return;
  }
  int zi = local / J.tilesPerZ, ti = local - zi * J.tilesPerZ;
  int ntx = J.C >> 5;
  int tx = ti % ntx, ty = ti / ntx;
  const float* ib = J.src + (long)zi * J.sIn;
  short* ob = J.dst + (long)zi * J.sOut;
  int c0 = tx * 32, r0 = ty * 32;
  int lx = threadIdx.x & 31, ly = threadIdx.x >> 5;
#pragma unroll
  for (int i = 0; i < 4; ++i)
    t[ly * 4 + i][lx] = ib[(long)(r0 + ly * 4 + i) * J.C + c0 + lx];
  __syncthreads();
#pragma unroll
  for (int i = 0; i < 4; ++i)
    ob[(long)(c0 + ly * 4 + i) * J.R + r0 + lx] = f2b(t[lx][ly * 4 + i] * J.scale);
}

// ---------------- bf16 MFMA BT-GEMM: C = A(MxK) @ Bt(NxK)^T ----------------
// 128x128 tile, BK=32, 256 thr. Prefetch pipeline. Requires K % 64 == 0.
// EPI: 0 = bf16 out, 1 = bias+exact-gelu bf16 out, 2 = fp32 out (partials).
template<int EPI>
__global__ __launch_bounds__(256) void k_mgemm(
    const short* __restrict__ A, const short* __restrict__ Bt,
    void* __restrict__ Cv, const float* __restrict__ bias,
    int K, int lda, int ldb, int ldc,
    long sA, long sB, long sC, int zdA, int zmA, int zdB, int zmB)
{
  __shared__ char As[8192];
  __shared__ char Bs[8192];
  int z = blockIdx.z;
  const short* Ab = A + ((long)((z / zdA) % zmA)) * sA;
  const short* Bb = Bt + ((long)((z / zdB) % zmB)) * sB;
  int t = threadIdx.x;
  int lane = t & 63, w = t >> 6;
  int wr = w >> 1, wc = w & 1;
  int g = lane >> 4, l15 = lane & 15;
  long row0 = (long)blockIdx.y * 128, col0 = (long)blockIdx.x * 128;
  const f32x4 zz = {0.f, 0.f, 0.f, 0.f};
  f32x4 acc[4][4];
#pragma unroll
  for (int m = 0; m < 4; ++m)
#pragma unroll
    for (int n = 0; n < 4; ++n) acc[m][n] = zz;

  auto mload = [&](s8v* aa, s8v* bb, int kk) {
#pragma unroll
    for (int i = 0; i < 2; ++i) {
      int r = i * 64 + (t >> 2), c = t & 3;
      aa[i] = *(const s8v*)&Ab[(row0 + r) * (long)lda + kk + c * 8];
      bb[i] = *(const s8v*)&Bb[(col0 + r) * (long)ldb + kk + c * 8];
    }
  };
  auto mstore = [&](s8v* aa, s8v* bb) {
#pragma unroll
    for (int i = 0; i < 2; ++i) {
      int r = i * 64 + (t >> 2), c = t & 3;
      int off = (r * 64 + c * 16) ^ ((r & 7) << 4);
      *(s8v*)&As[off] = aa[i];
      *(s8v*)&Bs[off] = bb[i];
    }
  };
  auto mcomp = [&]() {
    s8v af[4], bfr[4];
#pragma unroll
    for (int m = 0; m < 4; ++m) {
      int r = wr * 64 + m * 16 + l15;
      af[m] = *(const s8v*)&As[(r * 64 + g * 16) ^ ((r & 7) << 4)];
    }
#pragma unroll
    for (int n = 0; n < 4; ++n) {
      int r = wc * 64 + n * 16 + l15;
      bfr[n] = *(const s8v*)&Bs[(r * 64 + g * 16) ^ ((r & 7) << 4)];
    }
#pragma unroll
    for (int m = 0; m < 4; ++m)
#pragma unroll
      for (int n = 0; n < 4; ++n)
        acc[m][n] = __builtin_amdgcn_mfma_f32_16x16x32_bf16(af[m], bfr[n], acc[m][n], 0, 0, 0);
  };

  s8v a0[2], b0[2], a1[2], b1[2];
  mload(a0, b0, 0);
  for (int k0 = 0; k0 < K; k0 += 64) {
    __syncthreads(); mstore(a0, b0); __syncthreads();
    mload(a1, b1, k0 + 32);
    mcomp();
    __syncthreads(); mstore(a1, b1); __syncthreads();
    if (k0 + 64 < K) mload(a0, b0, k0 + 64);
    mcomp();
  }

  long zo = (long)z * sC;
#pragma unroll
  for (int m = 0; m < 4; ++m)
#pragma unroll
    for (int n = 0; n < 4; ++n)
#pragma unroll
      for (int r = 0; r < 4; ++r) {
        long rr = row0 + wr * 64 + m * 16 + g * 4 + r;
        long cc = col0 + wc * 64 + n * 16 + l15;
        float v = acc[m][n][r];
        if (EPI == 1) {
          v += bias[cc];
          v = 0.5f * v * (1.f + erff(v * 0.70710678118654752f));
        }
        if (EPI == 2)
          ((float*)Cv)[zo + rr * ldc + cc] = v;
        else
          ((short*)Cv)[zo + rr * ldc + cc] = f2b(v);
      }
}

// ---------------- MFMA flash attention v5 (head dim 256, 32x32 MFMA) -----
// 8 waves x 32 q-rows = 256 q/block, KVBLK=64, swapped QK^T (mfma(K,Q)) so
// each lane owns one q-row's P in registers; in-register softmax; P->PV
// A-frags via cvt_pk + cross-half shfl (no LDS P bounce). kv-split x4.
// K-tile 64x256 (full 32-row XOR swizzle, conflict-free); Vt-tile 256x64
// (3-bit swizzle). Double-buffered global_load_lds. Scale pre-folded into Wq.
__global__ __launch_bounds__(512, 2) void k_mflash5(
    const short* __restrict__ Qp, const short* __restrict__ Kp,
    const short* __restrict__ Vtp, short* __restrict__ Opart,
    float* __restrict__ MLp,
    int nk, int ldq, int ldk, int ldvt,
    long qh, long qb, long kh, long kb, long vh, long vb)
{
  __shared__ char pool[131072];  // 2 x (K 32KB + V 32KB)
  int t = threadIdx.x, lane = t & 63, w = t >> 6;
  int l31 = lane & 31, hi = lane >> 5;
  int h = blockIdx.y, b = blockIdx.z;
  int kv = blockIdx.x & 3, qblk = blockIdx.x >> 2;
  const short* Q  = Qp  + (long)h * qh + (long)b * qb;
  const short* Kg = Kp  + (long)h * kh + (long)b * kb;
  const short* Vg = Vtp + (long)h * vh + (long)b * vb;
  int q0w = qblk * 256 + w * 32;
  int nkq = nk >> 2;
  int NIT = nkq >> 6;           // KVBLK = 64
  long k0 = (long)kv * nkq;

  // Q B-frags: lane = q-col (l31), k = hi*8+j within d-slice s
  s8v qf[16];
  {
    const short* Qrow = Q + (long)(q0w + l31) * ldq + hi * 8;
#pragma unroll
    for (int s = 0; s < 16; ++s) qf[s] = *(const s8v*)(Qrow + s * 16);
  }

  // staging byte-offsets (32-bit; linear LDS dest + inverse-swizzled source)
  const char* KgB = (const char*)Kg;
  const char* VgB = (const char*)Vg;
  unsigned koff[4], voff[4];
#pragma unroll
  for (int c = 0; c < 4; ++c) {
    int r = 8 * w + 2 * c + hi;                 // K tile row 0..63
    koff[c] = (unsigned)((k0 + r) * (long)ldk * 2) + ((l31 ^ (r & 31)) << 4);
    int rv = 32 * w + 8 * c + (lane >> 3);      // V tile row 0..255
    voff[c] = (unsigned)(((long)rv * ldvt + k0) * 2) + (((lane & 7) ^ (lane >> 3)) << 4);
  }
  const unsigned kStep = (unsigned)(64 * ldk * 2);

  auto stage = [&](int bsel) {
    char* kd = pool + bsel * 65536 + (w << 12);
    char* vd = kd + 32768;
#pragma unroll
    for (int c = 0; c < 4; ++c) { gl16(KgB + koff[c], kd + c * 1024); koff[c] += kStep; }
#pragma unroll
    for (int c = 0; c < 4; ++c) { gl16(VgB + voff[c], vd + c * 1024); voff[c] += 128; }
  };

  f32x16 accO[8];
#pragma unroll
  for (int n = 0; n < 8; ++n)
#pragma unroll
    for (int i = 0; i < 16; ++i) accO[n][i] = 0.f;
  float mrow = -1e30f, lrow = 0.f;

  stage(0);

  for (int it = 0; it < NIT; ++it) {
    int cur = it & 1;
    asm volatile("s_waitcnt vmcnt(0)" ::: "memory");
    __syncthreads();
    if (it + 1 < NIT) stage(cur ^ 1);
    const char* kls = pool + cur * 65536;
    const char* vls = kls + 32768;

    // S^T = mfma(K, Q): 2 M-tiles (k) x 16 d-slices; C col = q, row = k
    f32x16 sacc[2];
#pragma unroll
    for (int i = 0; i < 16; ++i) { sacc[0][i] = 0.f; sacc[1][i] = 0.f; }
    __builtin_amdgcn_s_setprio(1);
#pragma unroll
    for (int tt = 0; tt < 2; ++tt) {
      int r = tt * 32 + l31;
#pragma unroll
      for (int s = 0; s < 16; ++s) {
        s8v kf = *(const s8v*)&kls[r * 512 + (((2 * s + hi) ^ l31) << 4)];
        sacc[tt] = __builtin_amdgcn_mfma_f32_32x32x16_bf16(kf, qf[s], sacc[tt], 0, 0, 0);
      }
    }
    __builtin_amdgcn_s_setprio(0);

    // in-register softmax over 64 k (32 local + 32 in partner half)
    float mt = sacc[0][0];
#pragma unroll
    for (int i = 1; i < 16; ++i) mt = fmaxf(mt, sacc[0][i]);
#pragma unroll
    for (int i = 0; i < 16; ++i) mt = fmaxf(mt, sacc[1][i]);
    mt = fmaxf(mt, __shfl_xor(mt, 32));
    if (__any(mt - mrow > 8.f)) {       // defer-max (T13)
      float mn = fmaxf(mrow, mt);
      float al = __expf(mrow - mn);
      mrow = mn; lrow *= al;
#pragma unroll
      for (int r = 0; r < 16; ++r) {
        float alr = __shfl(al, (r & 3) + 8 * (r >> 2) + 4 * hi);
#pragma unroll
        for (int n = 0; n < 8; ++n) accO[n][r] *= alr;
      }
    }
    float ls = 0.f;
#pragma unroll
    for (int tt = 0; tt < 2; ++tt)
#pragma unroll
      for (int i = 0; i < 16; ++i) {
        float p = __expf(sacc[tt][i] - mrow);
        sacc[tt][i] = p; ls += p;
      }
    ls += __shfl_xor(ls, 32);
    lrow += ls;

    // PV A-frags: slice s k-range [s*16,s*16+16); lane has k offsets
    // {0..3,8..11}+4*hi (regs r0..r0+7); exchange halves for the missing 8.
    s8v pa[4];
#pragma unroll
    for (int s = 0; s < 4; ++s) {
      int tt = s >> 1, r0 = (s & 1) * 8;
      unsigned w0 = cvtpk(sacc[tt][r0 + 0], sacc[tt][r0 + 1]);
      unsigned w1 = cvtpk(sacc[tt][r0 + 2], sacc[tt][r0 + 3]);
      unsigned w2 = cvtpk(sacc[tt][r0 + 4], sacc[tt][r0 + 5]);
      unsigned w3 = cvtpk(sacc[tt][r0 + 6], sacc[tt][r0 + 7]);
      unsigned x0 = (unsigned)__shfl_xor((int)w0, 32);
      unsigned x1 = (unsigned)__shfl_xor((int)w1, 32);
      unsigned x2 = (unsigned)__shfl_xor((int)w2, 32);
      unsigned x3 = (unsigned)__shfl_xor((int)w3, 32);
      u32x4 pw;
      pw.x = hi ? x2 : w0;
      pw.y = hi ? x3 : w1;
      pw.z = hi ? w2 : x0;
      pw.w = hi ? w3 : x1;
      pa[s] = *(s8v*)&pw;
    }

    // O += P @ V: 8 d-tiles x 4 k-slices; B = Vt (col = d, k = hi*8+j)
    __builtin_amdgcn_s_setprio(1);
#pragma unroll
    for (int n = 0; n < 8; ++n) {
      int rv = n * 32 + l31;
#pragma unroll
      for (int s2 = 0; s2 < 4; ++s2) {
        s8v vf = *(const s8v*)&vls[rv * 128 + (((2 * s2 + hi) ^ (l31 & 7)) << 4)];
        accO[n] = __builtin_amdgcn_mfma_f32_32x32x16_bf16(pa[s2], vf, accO[n], 0, 0, 0);
      }
    }
    __builtin_amdgcn_s_setprio(0);
  }

  // write partials: O unnormalized bf16, (m,l) fp32
  long prow = (((long)kv * 4 + b) * 8 + h) * 512;
  short* Ob = Opart + prow * 256;
  float* MLb = MLp + prow * 2;
  if (lane < 32) {
    MLb[(q0w + l31) * 2] = mrow;
    MLb[(q0w + l31) * 2 + 1] = lrow;
  }
#pragma unroll
  for (int n = 0; n < 8; ++n)
#pragma unroll
    for (int r = 0; r < 16; ++r) {
      int q = q0w + (r & 3) + 8 * (r >> 2) + 4 * hi;
      Ob[(long)q * 256 + n * 32 + l31] = f2b(accO[n][r]);
    }
}

// ---------------- combine 4 kv partials -> bufO bf16 ----------------
__global__ __launch_bounds__(512) void k_fcomb(
    const short* __restrict__ Op, const float* __restrict__ ML,
    short* __restrict__ O)
{
  int d = threadIdx.x & 255;
  int q = blockIdx.x * 2 + (threadIdx.x >> 8);
  int h = blockIdx.y, b = blockIdx.z;
  const long kvs = 4L * 8 * 512;  // rows per kv slice
  long r0 = ((long)b * 8 + h) * 512 + q;
  float mm[4], ll[4], m = -1e30f;
#pragma unroll
  for (int kv = 0; kv < 4; ++kv) {
    mm[kv] = ML[(kv * kvs + r0) * 2];
    ll[kv] = ML[(kv * kvs + r0) * 2 + 1];
    m = fmaxf(m, mm[kv]);
  }
  float wv[4], lsum = 0.f;
#pragma unroll
  for (int kv = 0; kv < 4; ++kv) { wv[kv] = __expf(mm[kv] - m); lsum += ll[kv] * wv[kv]; }
  float inv = 1.f / lsum, acc = 0.f;
#pragma unroll
  for (int kv = 0; kv < 4; ++kv)
    acc += b2f(Op[(kv * kvs + r0) * 256 + d]) * wv[kv];
  O[(long)b * 1048576 + (long)q * 2048 + h * 256 + d] = f2b(acc * inv);
}

// ---------------- z = LN(sum(Ypart) + bias + res) ----------------
__global__ __launch_bounds__(256) void k_bias_res_ln(
    const float* __restrict__ Yp, int nPart, long pStride,
    const float* __restrict__ bias,
    const float* __restrict__ res, int resMod,
    const float* __restrict__ g, const float* __restrict__ bta,
    float* __restrict__ out, short* __restrict__ out_bf)
{
  __shared__ float red[4];
  int row = blockIdx.x, e = threadIdx.x;
  float v = bias[e] + res[(long)(row % resMod) * 256 + e];
  for (int s = 0; s < nPart; ++s) v += Yp[s * pStride + (long)row * 256 + e];
  float s1 = v;
#pragma unroll
  for (int o = 32; o > 0; o >>= 1) s1 += __shfl_down(s1, o);
  if ((e & 63) == 0) red[e >> 6] = s1;
  __syncthreads();
  float mean = (red[0] + red[1] + red[2] + red[3]) * (1.f / 256.f);
  float d = v - mean;
  __syncthreads();
  float s2 = d * d;
#pragma unroll
  for (int o = 32; o > 0; o >>= 1) s2 += __shfl_down(s2, o);
  if ((e & 63) == 0) red[e >> 6] = s2;
  __syncthreads();
  float var = (red[0] + red[1] + red[2] + red[3]) * (1.f / 256.f);
  float o = g[e] * d * rsqrtf(var + 1e-5f) + bta[e];
  out[(long)row * 256 + e] = o;
  out_bf[(long)row * 256 + e] = f2b(o);
}

// ---------------- fused mean-over-latents + classifier ----------------
__global__ __launch_bounds__(256) void k_meancls(
    const float* __restrict__ z, const float* __restrict__ w,
    const float* __restrict__ bias, float* __restrict__ out)
{
  __shared__ float zms[256];
  int b = blockIdx.y, e = threadIdx.x;
  float s = 0.f;
  for (int l = 0; l < 512; ++l) s += z[((long)b * 512 + l) * 256 + e];
  zms[e] = s * (1.f / 512.f);
  __syncthreads();
  int j = blockIdx.x * 256 + e;
  if (j >= 1000) return;
  float acc = bias[j];
  for (int e2 = 0; e2 < 256; ++e2) acc += zms[e2] * w[e2 * 1000 + j];
  out[b * 1000 + j] = acc;
}

extern "C" void kernel_launch(void* const* d_in, const int* in_sizes, int n_in,
                              void* d_out, int out_size, void* d_ws, size_t ws_size,
                              hipStream_t stream)
{
  (void)in_sizes; (void)n_in; (void)out_size; (void)ws_size;
  const float* x       = (const float*)d_in[0];
  const float* conv_w  = (const float*)d_in[1];
  const float* conv_b  = (const float*)d_in[2];
  const float* pos_emb = (const float*)d_in[3];
  const float* latents = (const float*)d_in[4];
  const float* ca_wq   = (const float*)d_in[5];
  const float* ca_wk   = (const float*)d_in[6];
  const float* ca_wv   = (const float*)d_in[7];
  const float* ca_wu   = (const float*)d_in[8];
  const float* ca_bu   = (const float*)d_in[9];
  const float* ca_ln_g = (const float*)d_in[10];
  const float* ca_ln_b = (const float*)d_in[11];
  const float* blk_wq  = (const float*)d_in[12];
  const float* blk_wk  = (const float*)d_in[13];
  const float* blk_wv  = (const float*)d_in[14];
  const float* blk_wu  = (const float*)d_in[15];
  const float* blk_bu  = (const float*)d_in[16];
  const float* blk_ln1_g = (const float*)d_in[17];
  const float* blk_ln1_b = (const float*)d_in[18];
  const float* blk_w1  = (const float*)d_in[19];
  const float* blk_b1  = (const float*)d_in[20];
  const float* blk_w2  = (const float*)d_in[21];
  const float* blk_b2  = (const float*)d_in[22];
  const float* blk_ln2_g = (const float*)d_in[23];
  const float* blk_ln2_b = (const float*)d_in[24];
  const float* cls_w   = (const float*)d_in[25];
  const float* cls_b   = (const float*)d_in[26];
  float* out = (float*)d_out;

  // ---- workspace layout (bf16 as short) ----
  short* wqT_ca = (short*)d_ws;            // 2048x256
  short* wkT_ca = wqT_ca + 524288;         // 2048x256
  short* wuT_ca = wkT_ca + 524288;         // 256x2048
  short* wv_ca  = wuT_ca + 524288;         // 256x2048
  short* lat_bf = wv_ca + 524288;          // 512x256
  short* wqkT   = lat_bf + 131072;         // 4 x (4096x256)
  short* wvT    = wqkT + 4194304;          // 4 x (2048x256)
  short* wuT_b  = wvT + 2097152;           // 4 x (256x2048)
  short* w1T    = wuT_b + 2097152;         // 4 x (1024x256)
  short* w2T    = w1T + 1048576;           // 4 x (256x1024)
  short* tok_bf = w2T + 1048576;           // 4 x 4096x256
  short* tokT   = tok_bf + 4194304;        // 4 x 256x4096
  short* qCA    = tokT + 4194304;          // 512x2048
  short* qtil   = qCA + 1048576;           // 8 x 512x256
  short* MstT   = qtil + 1048576;          // 256x2048
  short* VtB    = MstT + 524288;           // 32 x 256x512
  short* bufO   = VtB + 4194304;           // 4 x 512x2048
  short* h1     = bufO + 4194304;          // 2048x1024
  short* z_bf   = h1 + 2097152;            // 2048x256
  float* z      = (float*)(z_bf + 524288); // 2048x256 fp32
  float* zm     = z + 524288;              // 4x256 (spare)
  float* Ypart  = zm + 1024;               // 8 x 2048x256 fp32 (split-K partials)
  short* Opart  = (short*)(Ypart + 4194304); // 4 x (4x8x512x256) bf16 kv-partials
  float* MLp    = (float*)(Opart + 16777216); // 4 x (4x8x512x2) fp32
  short* QKb    = tok_bf;                  // alias: 2048x4096 (after CA)

  const float scale = 0.17677669529663687f; // 1/sqrt(32), folded into Wq
  const int BIG = 1 << 30;

  // ---- weight prep: one batched dispatch (Wq pre-scaled) ----
  TrJobs JB; int nj = 0, base = 0;
  auto addT = [&](const float* s, short* d, int R, int C, long sIn, long sOut,
                  int zc, float sc) {
    int tpz = (C >> 5) * (R >> 5);
    JB.j[nj] = {s, d, R, C, sIn, sOut, 0, tpz, zc, base, sc};
    base += tpz * zc; ++nj;
  };
  auto addC = [&](const float* s, short* d, int nelem) {
    int tpz = nelem >> 13;
    JB.j[nj] = {s, d, 0, 0, 0, 0, 1, tpz, 1, base, 1.f};
    base += tpz; ++nj;
  };
  addT(ca_wq, wqT_ca, 256, 2048, 0, 0, 1, scale);
  addT(ca_wk, wkT_ca, 256, 2048, 0, 0, 1, 1.f);
  addT(ca_wu, wuT_ca, 2048, 256, 0, 0, 1, 1.f);
  addT(blk_wq, wqkT, 256, 2048, 524288, 1048576, 4, scale);
  addT(blk_wk, wqkT + 524288, 256, 2048, 524288, 1048576, 4, 1.f);
  addT(blk_wv, wvT, 256, 2048, 524288, 524288, 4, 1.f);
  addT(blk_wu, wuT_b, 2048, 256, 524288, 524288, 4, 1.f);
  addT(blk_w1, w1T, 256, 1024, 262144, 262144, 4, 1.f);
  addT(blk_w2, w2T, 1024, 256, 262144, 262144, 4, 1.f);
  addC(ca_wv, wv_ca, 524288);
  addC(latents, lat_bf, 131072);
  k_trbatch<<<base, 256, 0, stream>>>(JB, nj);

  // ---- tokens ----
  k_tokens<<<16384, 256, 0, stream>>>(x, conv_w, conv_b, pos_emb, tok_bf);
  k_tr<__hip_bfloat16><<<dim3(8, 128, 4), 256, 0, stream>>>(
      (const __hip_bfloat16*)tok_bf, tokT, 4096, 256, 1048576, 1048576);

  // ---- cross-attention (W_K folded into Q; W_V*W_U folded into MstT) ----
  k_mgemm<0><<<dim3(16, 4, 1), 256, 0, stream>>>(
      lat_bf, wqT_ca, qCA, nullptr, 256, 256, 256, 2048, 0, 0, 0, 1, BIG, 1, BIG);
  k_mgemm<0><<<dim3(2, 4, 8), 256, 0, stream>>>(
      qCA, wkT_ca, qtil, nullptr, 256, 2048, 256, 256, 256, 65536, 131072, 1, 8, 1, 8);
  k_mgemm<0><<<dim3(2, 2, 8), 256, 0, stream>>>(
      wuT_ca, wv_ca, MstT, nullptr, 256, 2048, 2048, 2048, 256, 256, 256, 1, 8, 1, 8);
  // CA flash: Q=qtilde(h) [pre-scaled], K=tokens(b), Vt=tokensT(b)
  k_mflash5<<<dim3(8, 8, 4), 512, 0, stream>>>(
      qtil, tok_bf, tokT, Opart, MLp, 4096, 256, 256, 4096,
      131072L, 0L, 0L, 1048576L, 0L, 1048576L);
  k_fcomb<<<dim3(256, 8, 4), 512, 0, stream>>>(Opart, MLp, bufO);
  // Y = bufO(2048x2048) @ MstT^T, split-K x8 -> fp32 partials
  k_mgemm<2><<<dim3(2, 16, 8), 256, 0, stream>>>(
      bufO, MstT, Ypart, nullptr, 256, 2048, 2048, 256, 256, 256, 524288, 1, 8, 1, 8);
  k_bias_res_ln<<<2048, 256, 0, stream>>>(Ypart, 8, 524288L, ca_bu, latents, 512,
                                          ca_ln_g, ca_ln_b, z, z_bf);

  // ---- transformer blocks ----
  for (int d = 0; d < 4; ++d) {
    // [Q|K] = z @ [scale*wq wk]  -> QKb (2048 x 4096) bf16
    k_mgemm<0><<<dim3(32, 16, 1), 256, 0, stream>>>(
        z_bf, wqkT + (long)d * 1048576, QKb, nullptr,
        256, 256, 256, 4096, 0, 0, 0, 1, BIG, 1, BIG);
    // Vt(b,h) = wvT_h @ z_b^T  (256 x 512)
    k_mgemm<0><<<dim3(4, 2, 32), 256, 0, stream>>>(
        wvT + (long)d * 524288, z_bf, VtB, nullptr,
        256, 256, 256, 512, 65536, 131072, 131072, 1, 8, 8, BIG);
    // self flash
    k_mflash5<<<dim3(8, 8, 4), 512, 0, stream>>>(
        QKb, QKb + 2048, VtB, Opart, MLp, 512, 4096, 4096, 512,
        256L, 2097152L, 256L, 2097152L, 131072L, 1048576L);
    k_fcomb<<<dim3(256, 8, 4), 512, 0, stream>>>(Opart, MLp, bufO);
    // Y = bufO @ wu^T, split-K x8 -> fp32 partials
    k_mgemm<2><<<dim3(2, 16, 8), 256, 0, stream>>>(
        bufO, wuT_b + (long)d * 524288, Ypart, nullptr,
        256, 2048, 2048, 256, 256, 256, 524288, 1, 8, 1, 8);
    k_bias_res_ln<<<2048, 256, 0, stream>>>(Ypart, 8, 524288L, blk_bu + d * 256, z, 2048,
        blk_ln1_g + d * 256, blk_ln1_b + d * 256, z, z_bf);
    // h1 = gelu(z @ w1 + b1)
    k_mgemm<1><<<dim3(8, 16, 1), 256, 0, stream>>>(
        z_bf, w1T + (long)d * 262144, h1, blk_b1 + d * 1024,
        256, 256, 256, 1024, 0, 0, 0, 1, BIG, 1, BIG);
    // Y = h1 @ w2, split-K x8 (Ksub=128) -> fp32 partials
    k_mgemm<2><<<dim3(2, 16, 8), 256, 0, stream>>>(
        h1, w2T + (long)d * 262144, Ypart, nullptr,
        128, 1024, 1024, 256, 128, 128, 524288, 1, 8, 1, 8);
    k_bias_res_ln<<<2048, 256, 0, stream>>>(Ypart, 8, 524288L, blk_b2 + d * 256, z, 2048,
        blk_ln2_g + d * 256, blk_ln2_b + d * 256, z, z_bf);
  }

  k_meancls<<<dim3(4, 4), 256, 0, stream>>>(z, cls_w, cls_b, out);
}